// Round 12
// baseline (339.295 us; speedup 1.0000x reference)
//
#include <hip/hip_runtime.h>
#include <hip/hip_bf16.h>

#define NV 16384
#define DD 128

typedef __attribute__((ext_vector_type(8))) short bf16x8;
typedef __attribute__((ext_vector_type(8))) unsigned short ushort8v;
typedef __attribute__((ext_vector_type(4))) float f32x4;
typedef __attribute__((ext_vector_type(2))) int i32x2;
typedef long long i64;

#define ASCALE 16384.0f
#define INV_ASCALE (1.0f / 16384.0f)

__device__ __forceinline__ unsigned short f2bf(float x) {
  unsigned u = __builtin_bit_cast(unsigned, x);
  u = (u + 0x7FFFu + ((u >> 16) & 1u)) >> 16;   // round-to-nearest-even
  return (unsigned short)u;
}

__device__ __forceinline__ i64 pk8(f32x4 a, f32x4 b, float s) {
  int lo = 0, hi = 0;
  lo = __builtin_amdgcn_cvt_pk_fp8_f32(a[0] * s, a[1] * s, lo, false);
  lo = __builtin_amdgcn_cvt_pk_fp8_f32(a[2] * s, a[3] * s, lo, true);
  hi = __builtin_amdgcn_cvt_pk_fp8_f32(b[0] * s, b[1] * s, hi, false);
  hi = __builtin_amdgcn_cvt_pk_fp8_f32(b[2] * s, b[3] * s, hi, true);
  i32x2 r; r[0] = lo; r[1] = hi;
  return __builtin_bit_cast(i64, r);
}

// ---------------------------------------------------------------------------
// Kernel 1 (round 9 core + flag zeroing): MFMA dual-GEMM ra (f32) + t (fp8).
// ---------------------------------------------------------------------------
__global__ __launch_bounds__(256) void k_small(
    const float* __restrict__ h, const long long* __restrict__ ridx,
    const float* __restrict__ W, const float* __restrict__ LW,
    const float* __restrict__ RP, const float* __restrict__ bias,
    float* __restrict__ ws_ra, i32x2* __restrict__ tT8,
    int* __restrict__ flags)
{
  __shared__ unsigned short rw [64 * 128];    // 16 KB rwh bf16, swizzled
  __shared__ unsigned short Wts[128 * 128];   // 32 KB W^T bf16, swizzled
  __shared__ unsigned short LWts[128 * 128];  // 32 KB LW^T bf16, swizzled
  const int tid = threadIdx.x;
  const int r0  = blockIdx.x * 64;

  if (tid == 0) flags[blockIdx.x] = 0;   // one flag per mblk (256 blocks)

  {
    const int k  = tid >> 1;            // 0..127
    const int j0 = (tid & 1) * 64;      // j half
    const float* wr  = W  + k * DD + j0;
    const float* lwr = LW + k * DD + j0;
#pragma unroll 8
    for (int i = 0; i < 64; ++i) {
      const int j = j0 + i;
      const int off = j * 128 + (((k >> 3) ^ (j & 7)) << 3) + (k & 7);
      Wts [off] = f2bf(wr[i]);
      LWts[off] = f2bf(lwr[i]);
    }
  }

  {
    const int r  = tid >> 2;            // 0..63
    const int cc = tid & 3;             // 32-col chunk-quad
    const int v  = r0 + r;
    const int reg = ((int)ridx[v]) & 63;
    const float* hp = h  + (size_t)v * DD + cc * 32;
    const float* rp = RP + reg * DD + cc * 32;
#pragma unroll
    for (int i = 0; i < 4; ++i) {
      const f32x4 a  = *(const f32x4*)(hp + i * 8);
      const f32x4 b  = *(const f32x4*)(hp + i * 8 + 4);
      const f32x4 pa = *(const f32x4*)(rp + i * 8);
      const f32x4 pb = *(const f32x4*)(rp + i * 8 + 4);
      ushort8v pk;
#pragma unroll
      for (int q = 0; q < 4; ++q) {
        pk[q]     = f2bf(a[q] * pa[q]);
        pk[4 + q] = f2bf(b[q] * pb[q]);
      }
      const int sc = (cc * 4 + i) ^ (r & 7);
      *(ushort8v*)&rw[r * 128 + sc * 8] = pk;
    }
  }
  __syncthreads();

  const int w = tid >> 6, lane = tid & 63, g = lane >> 4, l15 = lane & 15;
  f32x4 accA[8], accT[8];
#pragma unroll
  for (int f = 0; f < 8; ++f) {
    accA[f] = (f32x4){0.f, 0.f, 0.f, 0.f};
    accT[f] = (f32x4){0.f, 0.f, 0.f, 0.f};
  }
  const int arow = w * 16 + l15;
#pragma unroll
  for (int s = 0; s < 4; ++s) {
    const int sca = (s * 4 + g) ^ (l15 & 7);
    const bf16x8 af = *(const bf16x8*)&rw[arow * 128 + sca * 8];
#pragma unroll
    for (int f = 0; f < 8; ++f) {
      const int j = f * 16 + l15;
      const int scb = (s * 4 + g) ^ (l15 & 7);
      const bf16x8 bw = *(const bf16x8*)&Wts [j * 128 + scb * 8];
      accA[f] = __builtin_amdgcn_mfma_f32_16x16x32_bf16(af, bw, accA[f], 0, 0, 0);
      const bf16x8 bl = *(const bf16x8*)&LWts[j * 128 + scb * 8];
      accT[f] = __builtin_amdgcn_mfma_f32_16x16x32_bf16(af, bl, accT[f], 0, 0, 0);
    }
  }

#pragma unroll
  for (int f = 0; f < 8; ++f) {
    const int col = f * 16 + l15;
    const float bj = bias[col];
#pragma unroll
    for (int q = 0; q < 4; ++q) {
      const int v = r0 + w * 16 + g * 4 + q;
      ws_ra[(size_t)v * DD + col] = accA[f][q] + bj;
    }
  }
#pragma unroll
  for (int f = 0; f < 8; ++f) {
    const int j = f * 16 + l15;
    int own = 0;
    own = __builtin_amdgcn_cvt_pk_fp8_f32(accT[f][0], accT[f][1], own, false);
    own = __builtin_amdgcn_cvt_pk_fp8_f32(accT[f][2], accT[f][3], own, true);
    const int partner = __shfl_xor(own, 16, 64);
    if ((g & 1) == 0) {
      const int v0 = r0 + w * 16 + g * 4;      // multiple of 8
      i32x2 val; val[0] = own; val[1] = partner;
      tT8[(v0 >> 6) * 1024 + ((v0 >> 3) & 7) * 128 + j] = val;
    }
  }
}

// ---------------------------------------------------------------------------
// Kernel 2: partial rb = adj[rows, khalf] @ t[khalf] + FUSED last-finisher
// reduce.  BM=64, BK=64, fp8, split-K x2.  R11 main loop unchanged (A via
// global_load_lds 1KB whole-line staging, chunk-XOR swizzle, 3 bufs depth-2,
// vmcnt(6), K-rotation t0=mblk&127, XCD kh-partition).
// Epilogue: write own partial; fence; block-wide flag atomicAdd; the block
// drawing old==1 (second finisher, no spinning) combines both partials with
// ws_ra and writes out.  f32 add commutative -> bit-identical either way.
// ---------------------------------------------------------------------------
__global__ __launch_bounds__(256, 2) void k_big(
    const float* __restrict__ adj, const unsigned char* __restrict__ tTb,
    const float* __restrict__ ws_ra, float* __restrict__ part,
    int* __restrict__ flags, float* __restrict__ out)
{
  __shared__ unsigned char Bs[3][24576] __attribute__((aligned(16)));
  __shared__ int s_old;
  const int tid  = threadIdx.x;
  const int w    = tid >> 6;
  const int lane = tid & 63;
  const int g    = lane >> 4;
  const int l15  = lane & 15;
  const int hb   = blockIdx.x;
  const int kh   = (hb & 7) >> 2;             // XCD partition: bid%8<4 -> kh0
  const int mblk = (hb >> 3) * 4 + (hb & 3);  // bijective remap (512 % 8 == 0)
  const int bid  = mblk * 2 + kh;             // part-buffer slot
  const int r0   = mblk * 64;
  const int t0   = mblk & 127;                // K-rotation over 128 tiles
  const unsigned char* bbase = tTb + (size_t)kh * 128 * 8192;

#define RT(t) ((t0 + (t)) & 127)

  // per-lane pre-swizzled A staging sources (i = 0..3, 4 rows per instr)
  const float* asrc[4];
#pragma unroll
  for (int i = 0; i < 4; ++i) {
    const int rrel = w * 16 + i * 4 + (lane >> 4);        // row within tile
    const int cswz = (lane & 15) ^ ((i * 4 + (lane >> 4)) & 7);
    asrc[i] = adj + (size_t)(r0 + rrel) * NV + kh * (NV / 2) + cswz * 4;
  }

  f32x4 acc[8];
#pragma unroll
  for (int f = 0; f < 8; ++f) acc[f] = (f32x4){0.f, 0.f, 0.f, 0.f};

#define STAGE(bufidx, rt) do {                                                 \
    _Pragma("unroll")                                                          \
    for (int i_ = 0; i_ < 4; ++i_) {   /* A: 4 instrs, 4 rows x 256B each */   \
      const float* srcA_ = asrc[i_] + (size_t)(rt) * 64;                       \
      unsigned char* dstA_ = &Bs[bufidx][(w * 16 + i_ * 4) * 256];             \
      __builtin_amdgcn_global_load_lds(                                        \
          (const __attribute__((address_space(1))) unsigned int*)srcA_,        \
          (__attribute__((address_space(3))) unsigned int*)dstA_, 16, 0, 0);   \
    }                                                                          \
    _Pragma("unroll")                                                          \
    for (int i_ = 0; i_ < 2; ++i_) {   /* B: 2 instrs */                       \
      const int unit_ = i_ * 4 + w;                                            \
      const unsigned char* srcB_ = bbase + (size_t)(rt) * 8192 +               \
                                   unit_ * 1024 + lane * 16;                   \
      unsigned char* dstB_ = &Bs[bufidx][16384 + unit_ * 1024];                \
      __builtin_amdgcn_global_load_lds(                                        \
          (const __attribute__((address_space(1))) unsigned int*)srcB_,        \
          (__attribute__((address_space(3))) unsigned int*)dstB_, 16, 0, 0);   \
    } } while (0)

#define COMP(bufidx) do {                                                      \
    const unsigned char* Ab_ = &Bs[bufidx][(w * 16 + l15) * 256];              \
    const int x_ = l15 & 7;                                                    \
    const f32x4 c0_ = *(const f32x4*)&Ab_[((2 * g)     ^ x_) * 16];            \
    const f32x4 c1_ = *(const f32x4*)&Ab_[((2 * g + 1) ^ x_) * 16];            \
    const f32x4 c2_ = *(const f32x4*)&Ab_[((8 + 2 * g)     ^ x_) * 16];        \
    const f32x4 c3_ = *(const f32x4*)&Ab_[((8 + 2 * g + 1) ^ x_) * 16];        \
    const i64 a0_ = pk8(c0_, c1_, ASCALE);                                     \
    const i64 a1_ = pk8(c2_, c3_, ASCALE);                                     \
    const unsigned char* Bb_ = &Bs[bufidx][16384];                             \
    _Pragma("unroll")                                                          \
    for (int f_ = 0; f_ < 8; ++f_) {                                           \
      const int jr8_ = (f_ * 16 + l15) * 8;                                    \
      acc[f_] = __builtin_amdgcn_mfma_f32_16x16x32_fp8_fp8(a0_,                \
          *(const i64*)&Bb_[g * 1024 + jr8_],       acc[f_], 0, 0, 0);         \
      acc[f_] = __builtin_amdgcn_mfma_f32_16x16x32_fp8_fp8(a1_,                \
          *(const i64*)&Bb_[(4 + g) * 1024 + jr8_], acc[f_], 0, 0, 0);         \
    } } while (0)

#define VW6  asm volatile("s_waitcnt vmcnt(6)" ::: "memory")
#define VW0  asm volatile("s_waitcnt vmcnt(0)" ::: "memory")
#define BAR  __builtin_amdgcn_s_barrier()

  // prologue: tiles 0,1 in flight (6 ops each, tile-contiguous)
  STAGE(0, RT(0));
  STAGE(1, RT(1));

  // steady: iters 0..125 in triples (buf = t % 3), depth-2, vmcnt(6)
  for (int tq = 0; tq < 42; ++tq) {
    const int t = tq * 3;
    VW6; BAR; STAGE(2, RT(t + 2)); COMP(0);
    VW6; BAR; STAGE(0, RT(t + 3)); COMP(1);
    VW6; BAR; STAGE(1, RT(t + 4)); COMP(2);
  }
  // tail: iters 126 (buf 0), 127 (buf 1); loop already staged RT(127)
  VW6; BAR; COMP(0);
  VW0; BAR; COMP(1);

#undef STAGE
#undef COMP
#undef VW6
#undef VW0
#undef BAR
#undef RT

  // ---- epilogue: own partial, then last-finisher fused reduce ----
  float* pbase = part + ((size_t)bid * 64 + w * 16) * DD;
#pragma unroll
  for (int f = 0; f < 8; ++f) {
    const int col = f * 16 + l15;
#pragma unroll
    for (int q = 0; q < 4; ++q) {
      const int row = g * 4 + q;
      pbase[row * DD + col] = acc[f][q];
    }
  }
  __threadfence();          // release: partial visible before flag bump
  __syncthreads();          // all waves' stores issued before tid0 bumps
  if (tid == 0) s_old = atomicAdd(&flags[mblk], 1);
  __syncthreads();
  if (s_old == 1) {         // second finisher: partner's partial is visible
    __threadfence();        // acquire
    const int pbid = mblk * 2 + (kh ^ 1);
    const float* qbase  = part  + ((size_t)pbid * 64 + w * 16) * DD;
    const float* rabase = ws_ra + (size_t)(r0 + w * 16) * DD;
    float*       obase  = out   + (size_t)(r0 + w * 16) * DD;
#pragma unroll
    for (int f = 0; f < 8; ++f) {
      const int col = f * 16 + l15;
#pragma unroll
      for (int q = 0; q < 4; ++q) {
        const int row = g * 4 + q;
        obase[row * DD + col] =
            (acc[f][q] + qbase[row * DD + col]) * INV_ASCALE +
            rabase[row * DD + col];
      }
    }
  }
}

extern "C" void kernel_launch(void* const* d_in, const int* in_sizes, int n_in,
                              void* d_out, int out_size, void* d_ws, size_t ws_size,
                              hipStream_t stream) {
  const float*     h    = (const float*)d_in[0];
  const float*     adj  = (const float*)d_in[1];
  const long long* ridx = (const long long*)d_in[2];   // int64 per reference
  const float*     W    = (const float*)d_in[3];
  const float*     LW   = (const float*)d_in[4];
  const float*     RP   = (const float*)d_in[5];
  const float*     bias = (const float*)d_in[6];
  float* out = (float*)d_out;

  float* ws_ra = (float*)d_ws;                                    // 8 MB @ 0
  void*  tT8   = (void*)((char*)d_ws + (size_t)8  * 1024 * 1024); // 2 MB @ 8M
  float* part  = (float*)((char*)d_ws + (size_t)16 * 1024 * 1024);// 16 MB @ 16M
  int*   flags = (int*)((char*)d_ws + (size_t)32 * 1024 * 1024);  // 1 KB @ 32M

  hipLaunchKernelGGL(k_small, dim3(NV / 64), dim3(256), 0, stream,
                     h, ridx, W, LW, RP, bias, ws_ra, (i32x2*)tT8, flags);
  hipLaunchKernelGGL(k_big, dim3(NV / 64 * 2), dim3(256), 0, stream,
                     adj, (const unsigned char*)tT8, ws_ra, part, flags, out);
}

// Round 13
// 186.196 us; speedup vs baseline: 1.8222x; 1.8222x over previous
//
#include <hip/hip_runtime.h>
#include <hip/hip_bf16.h>

#define NV 16384
#define DD 128

typedef __attribute__((ext_vector_type(8))) short bf16x8;
typedef __attribute__((ext_vector_type(8))) unsigned short ushort8v;
typedef __attribute__((ext_vector_type(4))) float f32x4;
typedef __attribute__((ext_vector_type(2))) int i32x2;
typedef long long i64;

#define ASCALE 16384.0f
#define INV_ASCALE (1.0f / 16384.0f)

__device__ __forceinline__ unsigned short f2bf(float x) {
  unsigned u = __builtin_bit_cast(unsigned, x);
  u = (u + 0x7FFFu + ((u >> 16) & 1u)) >> 16;   // round-to-nearest-even
  return (unsigned short)u;
}

__device__ __forceinline__ i64 pk8(f32x4 a, f32x4 b, float s) {
  int lo = 0, hi = 0;
  lo = __builtin_amdgcn_cvt_pk_fp8_f32(a[0] * s, a[1] * s, lo, false);
  lo = __builtin_amdgcn_cvt_pk_fp8_f32(a[2] * s, a[3] * s, lo, true);
  hi = __builtin_amdgcn_cvt_pk_fp8_f32(b[0] * s, b[1] * s, hi, false);
  hi = __builtin_amdgcn_cvt_pk_fp8_f32(b[2] * s, b[3] * s, hi, true);
  i32x2 r; r[0] = lo; r[1] = hi;
  return __builtin_bit_cast(i64, r);
}

// ---------------------------------------------------------------------------
// Kernel 1 (unchanged from round 9): MFMA dual-GEMM for ra (f32) + t (fp8).
// ---------------------------------------------------------------------------
__global__ __launch_bounds__(256) void k_small(
    const float* __restrict__ h, const long long* __restrict__ ridx,
    const float* __restrict__ W, const float* __restrict__ LW,
    const float* __restrict__ RP, const float* __restrict__ bias,
    float* __restrict__ ws_ra, i32x2* __restrict__ tT8)
{
  __shared__ unsigned short rw [64 * 128];    // 16 KB rwh bf16, swizzled
  __shared__ unsigned short Wts[128 * 128];   // 32 KB W^T bf16, swizzled
  __shared__ unsigned short LWts[128 * 128];  // 32 KB LW^T bf16, swizzled
  const int tid = threadIdx.x;
  const int r0  = blockIdx.x * 64;

  {
    const int k  = tid >> 1;            // 0..127
    const int j0 = (tid & 1) * 64;      // j half
    const float* wr  = W  + k * DD + j0;
    const float* lwr = LW + k * DD + j0;
#pragma unroll 8
    for (int i = 0; i < 64; ++i) {
      const int j = j0 + i;
      const int off = j * 128 + (((k >> 3) ^ (j & 7)) << 3) + (k & 7);
      Wts [off] = f2bf(wr[i]);
      LWts[off] = f2bf(lwr[i]);
    }
  }

  {
    const int r  = tid >> 2;            // 0..63
    const int cc = tid & 3;             // 32-col chunk-quad
    const int v  = r0 + r;
    const int reg = ((int)ridx[v]) & 63;
    const float* hp = h  + (size_t)v * DD + cc * 32;
    const float* rp = RP + reg * DD + cc * 32;
#pragma unroll
    for (int i = 0; i < 4; ++i) {
      const f32x4 a  = *(const f32x4*)(hp + i * 8);
      const f32x4 b  = *(const f32x4*)(hp + i * 8 + 4);
      const f32x4 pa = *(const f32x4*)(rp + i * 8);
      const f32x4 pb = *(const f32x4*)(rp + i * 8 + 4);
      ushort8v pk;
#pragma unroll
      for (int q = 0; q < 4; ++q) {
        pk[q]     = f2bf(a[q] * pa[q]);
        pk[4 + q] = f2bf(b[q] * pb[q]);
      }
      const int sc = (cc * 4 + i) ^ (r & 7);
      *(ushort8v*)&rw[r * 128 + sc * 8] = pk;
    }
  }
  __syncthreads();

  const int w = tid >> 6, lane = tid & 63, g = lane >> 4, l15 = lane & 15;
  f32x4 accA[8], accT[8];
#pragma unroll
  for (int f = 0; f < 8; ++f) {
    accA[f] = (f32x4){0.f, 0.f, 0.f, 0.f};
    accT[f] = (f32x4){0.f, 0.f, 0.f, 0.f};
  }
  const int arow = w * 16 + l15;
#pragma unroll
  for (int s = 0; s < 4; ++s) {
    const int sca = (s * 4 + g) ^ (l15 & 7);
    const bf16x8 af = *(const bf16x8*)&rw[arow * 128 + sca * 8];
#pragma unroll
    for (int f = 0; f < 8; ++f) {
      const int j = f * 16 + l15;
      const int scb = (s * 4 + g) ^ (l15 & 7);
      const bf16x8 bw = *(const bf16x8*)&Wts [j * 128 + scb * 8];
      accA[f] = __builtin_amdgcn_mfma_f32_16x16x32_bf16(af, bw, accA[f], 0, 0, 0);
      const bf16x8 bl = *(const bf16x8*)&LWts[j * 128 + scb * 8];
      accT[f] = __builtin_amdgcn_mfma_f32_16x16x32_bf16(af, bl, accT[f], 0, 0, 0);
    }
  }

#pragma unroll
  for (int f = 0; f < 8; ++f) {
    const int col = f * 16 + l15;
    const float bj = bias[col];
#pragma unroll
    for (int q = 0; q < 4; ++q) {
      const int v = r0 + w * 16 + g * 4 + q;
      ws_ra[(size_t)v * DD + col] = accA[f][q] + bj;
    }
  }
#pragma unroll
  for (int f = 0; f < 8; ++f) {
    const int j = f * 16 + l15;
    int own = 0;
    own = __builtin_amdgcn_cvt_pk_fp8_f32(accT[f][0], accT[f][1], own, false);
    own = __builtin_amdgcn_cvt_pk_fp8_f32(accT[f][2], accT[f][3], own, true);
    const int partner = __shfl_xor(own, 16, 64);
    if ((g & 1) == 0) {
      const int v0 = r0 + w * 16 + g * 4;      // multiple of 8
      i32x2 val; val[0] = own; val[1] = partner;
      tT8[(v0 >> 6) * 1024 + ((v0 >> 3) & 7) * 128 + j] = val;
    }
  }
}

// ---------------------------------------------------------------------------
// Kernel 2 (R11 + single change): A staging loads carry NT cache policy
// (aux=2).  Each A staging instr reads whole 128B lines exactly once, so
// evict-first cannot cause refetch (unlike R5's scattered reg loads) — it
// only protects the 4MB per-XCD L2s for the B (tT8) working set.
// Everything else identical to R11: split-K x2, BM=64 BK=64, A via
// global_load_lds 1KB whole-line staging + chunk-XOR swizzle, 3 bufs
// depth-2 vmcnt(6), K-rotation t0=mblk&127, XCD kh-partition.
// ---------------------------------------------------------------------------
__global__ __launch_bounds__(256, 2) void k_big(
    const float* __restrict__ adj, const unsigned char* __restrict__ tTb,
    float* __restrict__ part)
{
  __shared__ unsigned char Bs[3][24576] __attribute__((aligned(16)));
  const int tid  = threadIdx.x;
  const int w    = tid >> 6;
  const int lane = tid & 63;
  const int g    = lane >> 4;
  const int l15  = lane & 15;
  const int hb   = blockIdx.x;
  const int kh   = (hb & 7) >> 2;             // XCD partition: bid%8<4 -> kh0
  const int mblk = (hb >> 3) * 4 + (hb & 3);  // bijective remap (512 % 8 == 0)
  const int bid  = mblk * 2 + kh;             // part-buffer slot
  const int r0   = mblk * 64;
  const int t0   = mblk & 127;                // K-rotation over 128 tiles
  const unsigned char* bbase = tTb + (size_t)kh * 128 * 8192;

#define RT(t) ((t0 + (t)) & 127)

  // per-lane pre-swizzled A staging sources (i = 0..3, 4 rows per instr)
  const float* asrc[4];
#pragma unroll
  for (int i = 0; i < 4; ++i) {
    const int rrel = w * 16 + i * 4 + (lane >> 4);        // row within tile
    const int cswz = (lane & 15) ^ ((i * 4 + (lane >> 4)) & 7);
    asrc[i] = adj + (size_t)(r0 + rrel) * NV + kh * (NV / 2) + cswz * 4;
  }

  f32x4 acc[8];
#pragma unroll
  for (int f = 0; f < 8; ++f) acc[f] = (f32x4){0.f, 0.f, 0.f, 0.f};

#define STAGE(bufidx, rt) do {                                                 \
    _Pragma("unroll")                                                          \
    for (int i_ = 0; i_ < 4; ++i_) {   /* A: 4 instrs, 4 rows x 256B, NT */    \
      const float* srcA_ = asrc[i_] + (size_t)(rt) * 64;                       \
      unsigned char* dstA_ = &Bs[bufidx][(w * 16 + i_ * 4) * 256];             \
      __builtin_amdgcn_global_load_lds(                                        \
          (const __attribute__((address_space(1))) unsigned int*)srcA_,        \
          (__attribute__((address_space(3))) unsigned int*)dstA_, 16, 0, 2);   \
    }                                                                          \
    _Pragma("unroll")                                                          \
    for (int i_ = 0; i_ < 2; ++i_) {   /* B: 2 instrs, normal caching */       \
      const int unit_ = i_ * 4 + w;                                            \
      const unsigned char* srcB_ = bbase + (size_t)(rt) * 8192 +               \
                                   unit_ * 1024 + lane * 16;                   \
      unsigned char* dstB_ = &Bs[bufidx][16384 + unit_ * 1024];                \
      __builtin_amdgcn_global_load_lds(                                        \
          (const __attribute__((address_space(1))) unsigned int*)srcB_,        \
          (__attribute__((address_space(3))) unsigned int*)dstB_, 16, 0, 0);   \
    } } while (0)

#define COMP(bufidx) do {                                                      \
    const unsigned char* Ab_ = &Bs[bufidx][(w * 16 + l15) * 256];              \
    const int x_ = l15 & 7;                                                    \
    const f32x4 c0_ = *(const f32x4*)&Ab_[((2 * g)     ^ x_) * 16];            \
    const f32x4 c1_ = *(const f32x4*)&Ab_[((2 * g + 1) ^ x_) * 16];            \
    const f32x4 c2_ = *(const f32x4*)&Ab_[((8 + 2 * g)     ^ x_) * 16];        \
    const f32x4 c3_ = *(const f32x4*)&Ab_[((8 + 2 * g + 1) ^ x_) * 16];        \
    const i64 a0_ = pk8(c0_, c1_, ASCALE);                                     \
    const i64 a1_ = pk8(c2_, c3_, ASCALE);                                     \
    const unsigned char* Bb_ = &Bs[bufidx][16384];                             \
    _Pragma("unroll")                                                          \
    for (int f_ = 0; f_ < 8; ++f_) {                                           \
      const int jr8_ = (f_ * 16 + l15) * 8;                                    \
      acc[f_] = __builtin_amdgcn_mfma_f32_16x16x32_fp8_fp8(a0_,                \
          *(const i64*)&Bb_[g * 1024 + jr8_],       acc[f_], 0, 0, 0);         \
      acc[f_] = __builtin_amdgcn_mfma_f32_16x16x32_fp8_fp8(a1_,                \
          *(const i64*)&Bb_[(4 + g) * 1024 + jr8_], acc[f_], 0, 0, 0);         \
    } } while (0)

#define VW6  asm volatile("s_waitcnt vmcnt(6)" ::: "memory")
#define VW0  asm volatile("s_waitcnt vmcnt(0)" ::: "memory")
#define BAR  __builtin_amdgcn_s_barrier()

  // prologue: tiles 0,1 in flight (6 ops each, tile-contiguous)
  STAGE(0, RT(0));
  STAGE(1, RT(1));

  // steady: iters 0..125 in triples (buf = t % 3), depth-2, vmcnt(6)
  for (int tq = 0; tq < 42; ++tq) {
    const int t = tq * 3;
    VW6; BAR; STAGE(2, RT(t + 2)); COMP(0);
    VW6; BAR; STAGE(0, RT(t + 3)); COMP(1);
    VW6; BAR; STAGE(1, RT(t + 4)); COMP(2);
  }
  // tail: iters 126 (buf 0), 127 (buf 1); loop already staged RT(127)
  VW6; BAR; COMP(0);
  VW0; BAR; COMP(1);

#undef STAGE
#undef COMP
#undef VW6
#undef VW0
#undef BAR
#undef RT

  // partial write: part[bid][64][128], row=g*4+q, col=f*16+l15 (C/D layout)
  float* pbase = part + ((size_t)bid * 64 + w * 16) * DD;
#pragma unroll
  for (int f = 0; f < 8; ++f) {
    const int col = f * 16 + l15;
#pragma unroll
    for (int q = 0; q < 4; ++q) {
      const int row = g * 4 + q;
      pbase[row * DD + col] = acc[f][q];
    }
  }
}

// ---------------------------------------------------------------------------
// Kernel 3: out = (part0 + part1) * 2^-14 + ws_ra   (deterministic reduce)
// ---------------------------------------------------------------------------
__global__ __launch_bounds__(256) void k_reduce(
    const float* __restrict__ part, const float* __restrict__ ws_ra,
    float* __restrict__ out)
{
  const size_t e = ((size_t)blockIdx.x * 256 + threadIdx.x) * 4;
  const int    mblk  = (int)(e >> 13);
  const int    local = (int)(e & 8191);
  const f32x4 p0 = *(const f32x4*)&part[(size_t)(2 * mblk)     * 8192 + local];
  const f32x4 p1 = *(const f32x4*)&part[(size_t)(2 * mblk + 1) * 8192 + local];
  const f32x4 ra = *(const f32x4*)&ws_ra[e];
  f32x4 o;
#pragma unroll
  for (int i = 0; i < 4; ++i) o[i] = (p0[i] + p1[i]) * INV_ASCALE + ra[i];
  *(f32x4*)&out[e] = o;
}

extern "C" void kernel_launch(void* const* d_in, const int* in_sizes, int n_in,
                              void* d_out, int out_size, void* d_ws, size_t ws_size,
                              hipStream_t stream) {
  const float*     h    = (const float*)d_in[0];
  const float*     adj  = (const float*)d_in[1];
  const long long* ridx = (const long long*)d_in[2];   // int64 per reference
  const float*     W    = (const float*)d_in[3];
  const float*     LW   = (const float*)d_in[4];
  const float*     RP   = (const float*)d_in[5];
  const float*     bias = (const float*)d_in[6];
  float* out = (float*)d_out;

  float* ws_ra = (float*)d_ws;                                    // 8 MB @ 0
  void*  tT8   = (void*)((char*)d_ws + (size_t)8  * 1024 * 1024); // 2 MB @ 8M
  float* part  = (float*)((char*)d_ws + (size_t)16 * 1024 * 1024);// 16 MB @ 16M

  hipLaunchKernelGGL(k_small, dim3(NV / 64), dim3(256), 0, stream,
                     h, ridx, W, LW, RP, bias, ws_ra, (i32x2*)tT8);
  hipLaunchKernelGGL(k_big, dim3(NV / 64 * 2), dim3(256), 0, stream,
                     adj, (const unsigned char*)tT8, part);
  hipLaunchKernelGGL(k_reduce, dim3((NV * DD / 4) / 256), dim3(256), 0, stream,
                     part, ws_ra, out);
}